// Round 5
// baseline (238.885 us; speedup 1.0000x reference)
//
#include <hip/hip_runtime.h>
#include <math.h>

// Match numpy's separate mul/add roundings — no implicit FMA contraction.
// (Explicit __builtin_fmaf below is intentional and unaffected.)
#pragma clang fp contract(off)

#define TPB 256
#define ROWLEN 1024
#define ROWS_PER_WAVE 4

// Native clang vector type (required by __builtin_nontemporal_store;
// HIP's float4 is a class and is rejected by the builtin).
typedef float f32x4 __attribute__((ext_vector_type(4)));

// One WAVE handles 4 consecutive rows of 1024 f32, SOFTWARE-PIPELINED:
// row r+1's four dwordx4 loads are issued before row r's compute, so the
// ~900-cycle HBM load latency and the dependent shuffle-reduce chains
// overlap. (R4 post-mortem: one-row-per-wave was stall-bound at ~75 µs
// vs a ~13 µs VALU / ~31 µs HBM floor — every wave paid a cold vmcnt(0)
// stall plus two serial ds_swizzle chains with no work of its own to
// hide them.)
//
// Numerics — identical to the validated R4 path (absmax 4.27e-4):
//  - x/sf: double-float reciprocal (rh+rl) + exact-residual FMA ~= CR f32 div.
//  - q via f32 recip-mul: flips only at integer quotients (polynomial
//    continuous within 0.4% there) -> +-1 output quantum.
//  - exp_int: pure f32 mul/add/ldexp/floor, bit-identical to numpy.
//  - Row sum: per-lane u32 (exact), u64 wave-reduce, f64 once. Exact &
//    order-independent -> factor = floor(2^32/sum) matches the reference.
//  - Epilogue: f32 mul by precomputed f64-rounded reciprocals, <=1 ulp vs
//    numpy's f32 division -> rare +-1 A-quantum flips (3.9e-4 << 1.87e-3).
__global__ __launch_bounds__(TPB) void qsplit_int_softmax_kernel(
    const float* __restrict__ x,
    const float* __restrict__ scale_p,
    const float* __restrict__ thr_p,
    float* __restrict__ out)
{
    const int lane = threadIdx.x & 63;
    const int wid  = threadIdx.x >> 6;
    const int wave_gid = blockIdx.x * 4 + wid;
    const size_t row0 = (size_t)wave_gid * ROWS_PER_WAVE;
    const size_t base0 = row0 * ROWLEN + (size_t)lane * 4;

    const float sf  = scale_p[0];   // 0.05f
    const float thr = thr_p[0];     // 0.1f

    // ---- per-wave constants (f64 fine: once per wave) ----
    const double sfd  = (double)sf;
    const double rd   = 1.0 / sfd;                 // 19.99999970197678
    const float  rh   = (float)rd;                 // 20.0f
    const float  rl   = (float)(rd - (double)rh);  // -1.25*2^-22 (exact)

    const double x0d    = floor(-0.69314718 / sfd);                  // -14
    const float  x0f    = (float)x0d;
    const float  bfc    = (float)floor((0.96963238 / 0.35815147) / sfd);   // 54
    const float  cfc    = (float)floor((1.0 / 0.35815147) / (sfd * sfd));  // 1116
    const float  clampf = (float)(15.0 * x0d);                       // -210
    const float  invx0f = (float)(1.0 / x0d);  // -0.071428575f

    const float  osA  = thr / 255.0f;        // f32, as numpy
    const float  osB  = 1.0f / 255.0f;
    const float  invA = (float)(1.0 / (4294967296.0 * (double)osA));
    const float  invB = (float)(1.0 / (4294967296.0 * (double)osB));
    const double thrq = floor((double)thr * 256.0);   // 25.0

    // ---- prime the pipeline: row 0 loads ----
    f32x4 cur[4], nxt[4];
    #pragma unroll
    for (int k = 0; k < 4; ++k)
        cur[k] = *(const f32x4*)(x + base0 + (size_t)k * 256);

    #pragma unroll
    for (int r = 0; r < ROWS_PER_WAVE; ++r) {
        const size_t rbase = base0 + (size_t)r * ROWLEN;

        // ---- prefetch next row BEFORE this row's compute ----
        if (r + 1 < ROWS_PER_WAVE) {
            #pragma unroll
            for (int k = 0; k < 4; ++k)
                nxt[k] = *(const f32x4*)(x + rbase + ROWLEN + (size_t)k * 256);
        }

        // ---- x_int = x/sf via double-float reciprocal (~CR f32 division) --
        float xi[16];
        #pragma unroll
        for (int k = 0; k < 4; ++k) {
            #pragma unroll
            for (int jj = 0; jj < 4; ++jj) {
                const float xx = cur[k][jj];
                const float p  = xx * rh;
                const float e  = __builtin_fmaf(xx, rh, -p);   // exact residual
                xi[k*4+jj]     = p + __builtin_fmaf(xx, rl, e);
            }
        }

        // ---- wave max (f32) ----
        float m = xi[0];
        #pragma unroll
        for (int j = 1; j < 16; ++j) m = fmaxf(m, xi[j]);
        #pragma unroll
        for (int off = 1; off < 64; off <<= 1)
            m = fmaxf(m, __shfl_xor(m, off));

        // ---- integer exp per element (all f32/int, bit-matching numpy) ----
        float e16[16];
        unsigned int usum = 0;   // exact: 16 * 3.66e7 < 2^31
        #pragma unroll
        for (int j = 0; j < 16; ++j) {
            float v = xi[j] - m;                 // exact f32 sub
            v = fmaxf(v, clampf);                // >= -210
            const float qf = floorf(v * invx0f); // in [0,15]
            const int   qi = (int)qf;
            const float r2 = v - x0f * qf;       // both steps exact in f32
            const float t  = r2 + bfc;
            const float z  = r2 * t + cfc;       // two roundings (contract off)
            float ei = floorf(ldexpf(z, 15 - qi)); // pow2 scale exact
            ei = fmaxf(ei, 0.0f);
            e16[j] = ei;
            usum += (unsigned int)ei;            // exact integer accumulation
        }

        // ---- wave sum: u64 shuffle reduce (exact, order-independent) ----
        unsigned long long wsum = usum;
        #pragma unroll
        for (int off = 1; off < 64; off <<= 1)
            wsum += __shfl_xor(wsum, off);
        const double s = (double)wsum;           // < 3.8e10 < 2^53: exact

        // ---- row-uniform epilogue constants ----
        const double factor_d = floor(4294967296.0 / s);
        const float  fac_f = (float)factor_d;
        const float  ath_f = (float)((thrq * s) * (1.0 / 256.0));

        // ---- per-element quantize + nontemporal store ----
        #pragma unroll
        for (int k = 0; k < 4; ++k) {
            f32x4 o;
            #pragma unroll
            for (int jj = 0; jj < 4; ++jj) {
                const float ei  = e16[k*4+jj];
                const bool  isA = (ei <= ath_f);
                const float t1  = ei * fac_f;               // bit-matches numpy
                const float t2  = t1 * (isA ? invA : invB); // ~f32 division
                float si = floorf(t2);
                si = fminf(si, isA ? 3.0e38f : 255.0f);     // cap only B path
                o[jj] = si * (isA ? osA : osB);
            }
            __builtin_nontemporal_store(o, (f32x4*)(out + rbase + (size_t)k * 256));
        }

        // ---- rotate pipeline regs ----
        if (r + 1 < ROWS_PER_WAVE) {
            #pragma unroll
            for (int k = 0; k < 4; ++k) cur[k] = nxt[k];
        }
    }
}

extern "C" void kernel_launch(void* const* d_in, const int* in_sizes, int n_in,
                              void* d_out, int out_size, void* d_ws, size_t ws_size,
                              hipStream_t stream) {
    const float* x     = (const float*)d_in[0];
    const float* scale = (const float*)d_in[1];
    const float* thr   = (const float*)d_in[2];
    float* out = (float*)d_out;

    const int total = in_sizes[0];           // 2*16*1024*1024
    const int rows  = total / ROWLEN;        // 32768
    const int waves = rows / ROWS_PER_WAVE;  // 8192
    const int blocks = waves / 4;            // 2048 blocks x 4 waves

    qsplit_int_softmax_kernel<<<dim3(blocks), dim3(TPB), 0, stream>>>(
        x, scale, thr, out);
}

// Round 6
// 231.463 us; speedup vs baseline: 1.0321x; 1.0321x over previous
//
#include <hip/hip_runtime.h>
#include <math.h>

// Match numpy's separate mul/add roundings — no implicit FMA contraction.
// (Explicit __builtin_fmaf below is intentional and unaffected.)
#pragma clang fp contract(off)

#define TPB 256
#define ROWLEN 1024

// Native clang vector type (required by __builtin_nontemporal_store).
typedef float f32x4 __attribute__((ext_vector_type(4)));

// ---- DPP wave64 reductions (VALU-only; no LDS pipe, ~4cyc/stage) ----
// LLVM atomic-optimizer sequence: within-row inclusive prefix via
// row_shr 1/2/4/8, then row_bcast15 (rows 1,3) + row_bcast31 (rows 2,3);
// lane 63 holds the full-wave result; readlane broadcasts via SGPR.
// Masked/invalid lanes receive `old` = the op identity.

__device__ __forceinline__ float wave_max_dpp(float m) {
    const int NEG_INF = 0xff800000;             // -inf bits (fmax identity)
    int v;
    v = __builtin_amdgcn_update_dpp(NEG_INF, __float_as_int(m), 0x111, 0xf, 0xf, false);
    m = fmaxf(m, __int_as_float(v));
    v = __builtin_amdgcn_update_dpp(NEG_INF, __float_as_int(m), 0x112, 0xf, 0xf, false);
    m = fmaxf(m, __int_as_float(v));
    v = __builtin_amdgcn_update_dpp(NEG_INF, __float_as_int(m), 0x114, 0xf, 0xf, false);
    m = fmaxf(m, __int_as_float(v));
    v = __builtin_amdgcn_update_dpp(NEG_INF, __float_as_int(m), 0x118, 0xf, 0xf, false);
    m = fmaxf(m, __int_as_float(v));
    v = __builtin_amdgcn_update_dpp(NEG_INF, __float_as_int(m), 0x142, 0xa, 0xf, false);
    m = fmaxf(m, __int_as_float(v));
    v = __builtin_amdgcn_update_dpp(NEG_INF, __float_as_int(m), 0x143, 0xc, 0xf, false);
    m = fmaxf(m, __int_as_float(v));
    return __int_as_float(__builtin_amdgcn_readlane(__float_as_int(m), 63));
}

__device__ __forceinline__ unsigned wave_sum_dpp_u32(unsigned a) {
    int v;
    v = __builtin_amdgcn_update_dpp(0, (int)a, 0x111, 0xf, 0xf, false); a += (unsigned)v;
    v = __builtin_amdgcn_update_dpp(0, (int)a, 0x112, 0xf, 0xf, false); a += (unsigned)v;
    v = __builtin_amdgcn_update_dpp(0, (int)a, 0x114, 0xf, 0xf, false); a += (unsigned)v;
    v = __builtin_amdgcn_update_dpp(0, (int)a, 0x118, 0xf, 0xf, false); a += (unsigned)v;
    v = __builtin_amdgcn_update_dpp(0, (int)a, 0x142, 0xa, 0xf, false); a += (unsigned)v;
    v = __builtin_amdgcn_update_dpp(0, (int)a, 0x143, 0xc, 0xf, false); a += (unsigned)v;
    return (unsigned)__builtin_amdgcn_readlane((int)a, 63);
}

// One WAVE per row of 1024 f32 (64 lanes x 16 elements), 4 rows per block.
// R5 post-mortem: no pipe >35% busy at 83µs — stall-bound on the two
// serial __shfl_xor (ds_swizzle, LDS-pipe) reduction chains in every
// row's critical path, and R5's pipelining traded away TLP. This round:
// max TLP (1 row/wave, 32768 waves) + DPP reductions (VALU-only).
//
// Numerics — identical to the validated R4 path (absmax 4.27e-4):
//  - x/sf: double-float reciprocal (rh+rl) + exact-residual FMA ~= CR f32 div.
//  - q via f32 recip-mul: flips only at integer quotients (polynomial
//    continuous within 0.4% there) -> +-1 output quantum.
//  - exp_int: pure f32 mul/add/ldexp/floor, bit-identical to numpy.
//  - Row sum: per-lane u32 (exact, <2^30); reduced as two u32 DPP chains
//    on lo16/hi16 halves (partial sums < 2^23 / 2^20: exact), recomposed
//    as (hi<<16)+lo in u64 — bit-identical to the exact u64 sum, so
//    factor = floor(2^32/sum) still matches the reference exactly.
//  - Epilogue: f32 mul by f64-rounded reciprocals, <=1 ulp vs numpy's f32
//    division -> rare +-1 A-quantum flips (3.9e-4 << 1.87e-3 threshold).
__global__ __launch_bounds__(TPB) void qsplit_int_softmax_kernel(
    const float* __restrict__ x,
    const float* __restrict__ scale_p,
    const float* __restrict__ thr_p,
    float* __restrict__ out)
{
    const int lane = threadIdx.x & 63;
    const int wid  = threadIdx.x >> 6;
    const int row  = blockIdx.x * 4 + wid;
    const size_t rbase = (size_t)row * ROWLEN + (size_t)lane * 4;

    const float sf  = scale_p[0];   // 0.05f
    const float thr = thr_p[0];     // 0.1f

    // ---- per-wave constants (f64 fine: once per wave) ----
    const double sfd  = (double)sf;
    const double rd   = 1.0 / sfd;                 // 19.99999970197678
    const float  rh   = (float)rd;                 // 20.0f
    const float  rl   = (float)(rd - (double)rh);  // -1.25*2^-22 (exact)

    const double x0d    = floor(-0.69314718 / sfd);                  // -14
    const float  x0f    = (float)x0d;
    const float  bfc    = (float)floor((0.96963238 / 0.35815147) / sfd);   // 54
    const float  cfc    = (float)floor((1.0 / 0.35815147) / (sfd * sfd));  // 1116
    const float  clampf = (float)(15.0 * x0d);                       // -210
    const float  invx0f = (float)(1.0 / x0d);  // -0.071428575f

    const float  osA  = thr / 255.0f;        // f32, as numpy
    const float  osB  = 1.0f / 255.0f;
    const float  invA = (float)(1.0 / (4294967296.0 * (double)osA));
    const float  invB = (float)(1.0 / (4294967296.0 * (double)osB));
    const double thrq = floor((double)thr * 256.0);   // 25.0

    // ---- load 16 elements (4x dwordx4 = 1KB contiguous per wave instr) ----
    f32x4 xv[4];
    #pragma unroll
    for (int k = 0; k < 4; ++k)
        xv[k] = *(const f32x4*)(x + rbase + (size_t)k * 256);

    // ---- x_int = x/sf via double-float reciprocal (~CR f32 division) ----
    float xi[16];
    #pragma unroll
    for (int k = 0; k < 4; ++k) {
        #pragma unroll
        for (int jj = 0; jj < 4; ++jj) {
            const float xx = xv[k][jj];
            const float p  = xx * rh;
            const float e  = __builtin_fmaf(xx, rh, -p);   // exact residual
            xi[k*4+jj]     = p + __builtin_fmaf(xx, rl, e);
        }
    }

    // ---- wave max: local tree + DPP chain ----
    float m = xi[0];
    #pragma unroll
    for (int j = 1; j < 16; ++j) m = fmaxf(m, xi[j]);
    m = wave_max_dpp(m);

    // ---- integer exp per element (all f32/int, bit-matching numpy) ----
    float e16[16];
    unsigned int usum = 0;   // exact: 16 * 3.66e7 < 2^30
    #pragma unroll
    for (int j = 0; j < 16; ++j) {
        float v = xi[j] - m;                 // exact f32 sub
        v = fmaxf(v, clampf);                // >= -210
        const float qf = floorf(v * invx0f); // in [0,15]
        const int   qi = (int)qf;
        const float r2 = v - x0f * qf;       // both steps exact in f32
        const float t  = r2 + bfc;
        const float z  = r2 * t + cfc;       // two roundings (contract off)
        float ei = floorf(ldexpf(z, 15 - qi)); // pow2 scale exact
        ei = fmaxf(ei, 0.0f);
        e16[j] = ei;
        usum += (unsigned int)ei;            // exact integer accumulation
    }

    // ---- wave sum: two parallel u32 DPP chains (lo16/hi16, both exact) ----
    const unsigned lo = wave_sum_dpp_u32(usum & 0xFFFFu);
    const unsigned hi = wave_sum_dpp_u32(usum >> 16);
    const unsigned long long ws = ((unsigned long long)hi << 16) + lo;
    const double s = (double)ws;             // < 3.8e10 < 2^53: exact

    // ---- row-uniform epilogue constants (f64 once per row) ----
    const double factor_d = floor(4294967296.0 / s);
    const float  fac_f = (float)factor_d;
    const float  ath_f = (float)((thrq * s) * (1.0 / 256.0));

    // ---- per-element quantize + nontemporal store ----
    #pragma unroll
    for (int k = 0; k < 4; ++k) {
        f32x4 o;
        #pragma unroll
        for (int jj = 0; jj < 4; ++jj) {
            const float ei  = e16[k*4+jj];
            const bool  isA = (ei <= ath_f);
            const float t1  = ei * fac_f;               // bit-matches numpy
            const float t2  = t1 * (isA ? invA : invB); // ~f32 division
            float si = floorf(t2);
            si = fminf(si, isA ? 3.0e38f : 255.0f);     // cap only B path
            o[jj] = si * (isA ? osA : osB);
        }
        __builtin_nontemporal_store(o, (f32x4*)(out + rbase + (size_t)k * 256));
    }
}

extern "C" void kernel_launch(void* const* d_in, const int* in_sizes, int n_in,
                              void* d_out, int out_size, void* d_ws, size_t ws_size,
                              hipStream_t stream) {
    const float* x     = (const float*)d_in[0];
    const float* scale = (const float*)d_in[1];
    const float* thr   = (const float*)d_in[2];
    float* out = (float*)d_out;

    const int total = in_sizes[0];        // 2*16*1024*1024
    const int rows  = total / ROWLEN;     // 32768
    const int blocks = rows / 4;          // one wave per row, 4 waves/block

    qsplit_int_softmax_kernel<<<dim3(blocks), dim3(TPB), 0, stream>>>(
        x, scale, thr, out);
}

// Round 7
// 224.368 us; speedup vs baseline: 1.0647x; 1.0316x over previous
//
#include <hip/hip_runtime.h>
#include <math.h>

// Match numpy's separate mul/add roundings — no implicit FMA contraction.
// (Explicit __builtin_fmaf below is intentional and unaffected.)
#pragma clang fp contract(off)

#define TPB 256
#define ROWLEN 1024

// Native clang vector type (required by __builtin_nontemporal_store).
typedef float f32x4 __attribute__((ext_vector_type(4)));

// ---- DPP wave64 reductions (VALU-only; ~4cyc/stage, no LDS pipe) ----
__device__ __forceinline__ float wave_max_dpp(float m) {
    const int NEG_INF = 0xff800000;             // -inf bits (fmax identity)
    int v;
    v = __builtin_amdgcn_update_dpp(NEG_INF, __float_as_int(m), 0x111, 0xf, 0xf, false);
    m = fmaxf(m, __int_as_float(v));
    v = __builtin_amdgcn_update_dpp(NEG_INF, __float_as_int(m), 0x112, 0xf, 0xf, false);
    m = fmaxf(m, __int_as_float(v));
    v = __builtin_amdgcn_update_dpp(NEG_INF, __float_as_int(m), 0x114, 0xf, 0xf, false);
    m = fmaxf(m, __int_as_float(v));
    v = __builtin_amdgcn_update_dpp(NEG_INF, __float_as_int(m), 0x118, 0xf, 0xf, false);
    m = fmaxf(m, __int_as_float(v));
    v = __builtin_amdgcn_update_dpp(NEG_INF, __float_as_int(m), 0x142, 0xa, 0xf, false);
    m = fmaxf(m, __int_as_float(v));
    v = __builtin_amdgcn_update_dpp(NEG_INF, __float_as_int(m), 0x143, 0xc, 0xf, false);
    m = fmaxf(m, __int_as_float(v));
    return __int_as_float(__builtin_amdgcn_readlane(__float_as_int(m), 63));
}

__device__ __forceinline__ unsigned wave_sum_dpp_u32(unsigned a) {
    int v;
    v = __builtin_amdgcn_update_dpp(0, (int)a, 0x111, 0xf, 0xf, false); a += (unsigned)v;
    v = __builtin_amdgcn_update_dpp(0, (int)a, 0x112, 0xf, 0xf, false); a += (unsigned)v;
    v = __builtin_amdgcn_update_dpp(0, (int)a, 0x114, 0xf, 0xf, false); a += (unsigned)v;
    v = __builtin_amdgcn_update_dpp(0, (int)a, 0x118, 0xf, 0xf, false); a += (unsigned)v;
    v = __builtin_amdgcn_update_dpp(0, (int)a, 0x142, 0xa, 0xf, false); a += (unsigned)v;
    v = __builtin_amdgcn_update_dpp(0, (int)a, 0x143, 0xc, 0xf, false); a += (unsigned)v;
    return (unsigned)__builtin_amdgcn_readlane((int)a, 63);
}

// BLOCK-per-row: 256 threads (4 waves) per row of 1024, 4 elems/thread
// (one dwordx4 each). R1 was this shape but f64-VALU-bound (76% busy);
// this is the lean-f32 version. Rationale: all 1-row-per-WAVE variants
// (R2,R4,R6) plateau at ~75-85us vs a ~45us memory floor with no pipe
// >35% busy — row critical path (4 serial line-groups + reduce chain +
// epilogue) appears to be the wall; this cuts it ~4x.
//
// Preamble is f32 double-float Newton (no per-wave f64 divisions — at
// 131072 waves the old f64 preamble would rival the compute itself).
// f64 survives only in factor/ath (~3 ops per block).
//
// Numerics vs the numpy f32 reference (validated family, absmax 4.27e-4):
//  - 1/sf, b, c, x0 via double-float (rh+rl ~ 2^-46 rel): floors land
//    far from boundaries (13.86->-14, 54.15->54, 1116.85->1116).
//  - x/sf: double-float multiply + exact-residual FMA ~= CR f32 division.
//  - exp_int: pure f32 mul/add/ldexp/floor — bit-identical to numpy.
//  - Row sum: per-lane u32 (<2^28, exact); per-wave lo16/hi16 DPP chains
//    (both < 2^22: exact); cross-wave as exact-integer doubles in LDS.
//    Order-independent => factor = floor(2^32/sum) exact (the one
//    catastrophic flip stays impossible).
//  - Epilogue reciprocals f32-rounded (<=1 ulp vs f32 division): rare
//    +-1 A-quantum flips, 3.9e-4 << 1.87e-3 threshold.
__global__ __launch_bounds__(TPB) void qsplit_int_softmax_kernel(
    const float* __restrict__ x,
    const float* __restrict__ scale_p,
    const float* __restrict__ thr_p,
    float* __restrict__ out)
{
    const int tid  = threadIdx.x;
    const int lane = tid & 63;
    const int wid  = tid >> 6;
    const size_t base = (size_t)blockIdx.x * ROWLEN + (size_t)tid * 4;

    __shared__ float  smax[4];
    __shared__ double ssum[4];

    const float sf  = scale_p[0];   // 0.05f
    const float thr = thr_p[0];     // 0.1f

    // ---- lean f32 preamble: double-float 1/sf ----
    const float rh = 1.0f / sf;                            // IEEE f32 div
    const float er = __builtin_fmaf(-sf, rh, 1.0f);        // residual
    const float rl = rh * er;                              // rh+rl ~ 1/sf @2^-46

    // q = a/sf in double-float, then floor (margins: .137/.147/.845)
    #define DF_DIV(a) ({ float _p = (a) * rh; \
                         float _e = __builtin_fmaf((a), rh, -_p); \
                         _p + __builtin_fmaf((a), rl, _e); })
    const float x0f    = floorf(DF_DIV(-0.69314718f));           // -14
    const float bfc    = floorf(DF_DIV(2.7073824f));             // 54  (c1/c0)
    const float s2     = sf * sf;
    const float r2h    = 1.0f / s2;
    const float r2e    = __builtin_fmaf(-s2, r2h, 1.0f);
    const float r2l    = r2h * r2e;
    const float cq     = __builtin_fmaf(2.7921141f, r2l,
                         2.7921141f * r2h);                      // c2/c0/sf^2
    const float cfc    = floorf(cq);                             // 1116
    const float clampf = 15.0f * x0f;                            // -210 exact
    const float invx0f = 1.0f / x0f;

    const float osA  = thr / 255.0f;         // f32 div, as numpy
    const float osB  = 1.0f / 255.0f;
    const float invA = 1.0f / (4294967296.0f * osA);   // <=1ulp vs CR div
    const float invB = 1.0f / (4294967296.0f * osB);
    const float thrq = floorf(thr * 256.0f);           // 25

    // ---- load 4 elements (one dwordx4/thread; block covers the row) ----
    const f32x4 xv = *(const f32x4*)(x + base);

    // ---- x_int = x/sf via double-float (~CR f32 division) ----
    float xi[4];
    #pragma unroll
    for (int j = 0; j < 4; ++j) {
        const float xx = xv[j];
        const float p  = xx * rh;
        const float e  = __builtin_fmaf(xx, rh, -p);   // exact residual
        xi[j] = p + __builtin_fmaf(xx, rl, e);
    }

    // ---- row max: local + DPP + tiny LDS cross-wave ----
    float m = fmaxf(fmaxf(xi[0], xi[1]), fmaxf(xi[2], xi[3]));
    m = wave_max_dpp(m);
    if (lane == 0) smax[wid] = m;
    __syncthreads();
    m = fmaxf(fmaxf(smax[0], smax[1]), fmaxf(smax[2], smax[3]));

    // ---- integer exp (f32/int, bit-matching numpy) ----
    float e4[4];
    unsigned usum = 0;    // <= 4 * 3.66e7 < 2^28: exact
    #pragma unroll
    for (int j = 0; j < 4; ++j) {
        float v = xi[j] - m;                  // exact f32 sub
        v = fmaxf(v, clampf);                 // >= -210
        const float qf = floorf(v * invx0f);  // in [0,15]; flips benign
        const int   qi = (int)qf;
        const float r  = v - x0f * qf;        // exact in f32
        const float t  = r + bfc;
        const float z  = r * t + cfc;         // two roundings (contract off)
        float ei = floorf(ldexpf(z, 15 - qi)); // pow2 scale exact
        ei = fmaxf(ei, 0.0f);
        e4[j] = ei;
        usum += (unsigned)ei;
    }

    // ---- row sum: lo/hi u32 DPP (exact) + exact-int doubles in LDS ----
    const unsigned lo = wave_sum_dpp_u32(usum & 0xFFFFu);  // < 2^22
    const unsigned hi = wave_sum_dpp_u32(usum >> 16);      // < 2^20
    if (lane == 0)
        ssum[wid] = (double)(((unsigned long long)hi << 16) + lo); // exact int
    __syncthreads();
    const double s = ((ssum[0] + ssum[1]) + ssum[2]) + ssum[3];    // exact

    // ---- row-uniform epilogue constants (f64: ~3 ops per block) ----
    const float fac_f = (float)floor(4294967296.0 / s);   // int < 2^17: exact
    const float ath_f = (float)(((double)thrq * s) * (1.0 / 256.0));

    // ---- quantize + nontemporal store ----
    f32x4 o;
    #pragma unroll
    for (int j = 0; j < 4; ++j) {
        const float ei  = e4[j];
        const bool  isA = (ei <= ath_f);
        const float t1  = ei * fac_f;               // bit-matches numpy
        const float t2  = t1 * (isA ? invA : invB); // ~f32 division
        float si = floorf(t2);
        si = fminf(si, isA ? 3.0e38f : 255.0f);     // cap only B path
        o[j] = si * (isA ? osA : osB);
    }
    __builtin_nontemporal_store(o, (f32x4*)(out + base));
}

extern "C" void kernel_launch(void* const* d_in, const int* in_sizes, int n_in,
                              void* d_out, int out_size, void* d_ws, size_t ws_size,
                              hipStream_t stream) {
    const float* x     = (const float*)d_in[0];
    const float* scale = (const float*)d_in[1];
    const float* thr   = (const float*)d_in[2];
    float* out = (float*)d_out;

    const int total = in_sizes[0];        // 2*16*1024*1024
    const int rows  = total / ROWLEN;     // 32768 blocks, one row each

    qsplit_int_softmax_kernel<<<dim3(rows), dim3(TPB), 0, stream>>>(
        x, scale, thr, out);
}